// Round 1
// baseline (1417.296 us; speedup 1.0000x reference)
//
#include <hip/hip_runtime.h>
#include <hip/hip_bf16.h>
#include <cstdint>

typedef __bf16 bf16x8 __attribute__((ext_vector_type(8)));
typedef float  f32x4  __attribute__((ext_vector_type(4)));

// ---------------- workspace layout (bytes) ----------------
constexpr size_t WTP_OFF  = 0;         // [24][256][192] bf16 (prolog W^T: o<192 = W_ih col, o>=192 = W_init col)
constexpr size_t WTHH_OFF = 2359296;   // [24][192][64]  bf16 (W_hh^T per node)
constexpr size_t WTFC_OFF = 2949120;   // [24][64][64]   bf16 (W_fc^T per node)
constexpr size_t GN_OFF   = 3145728;   // [4][24][24] f32, row-L1-normalized (init, ih, hh, fc)
constexpr size_t BGI_OFF  = 3154944;   // [24][192] f32: b_ih + (o<128 ? b_hh : 0)
constexpr size_t TWS_OFF  = 3173376;   // [2048][24][256] bf16 prolog per-node GEMM result
constexpr size_t GIWS_OFF = 28339200;  // [2048][192][24] bf16 (n innermost!) gi with biases folded
constexpr size_t H0WS_OFF = 47213568;  // [2048][24][64] bf16 h0
constexpr size_t WS_NEED  = 53505024;

__device__ __forceinline__ float bf2f(ushort u){
  union { uint32_t i; float f; } v; v.i = ((uint32_t)u) << 16; return v.f;
}
__device__ __forceinline__ ushort f2bf(float f){
  union { float f; uint32_t i; } v; v.f = f;
  return (ushort)((v.i + 0x7fffu + ((v.i >> 16) & 1u)) >> 16);
}
__device__ __forceinline__ f32x4 mfma16(bf16x8 a, bf16x8 b, f32x4 c){
  return __builtin_amdgcn_mfma_f32_16x16x32_bf16(a, b, c, 0, 0, 0);
}
__device__ __forceinline__ float sigmoidf_(float x){
  float e = __expf(-x); return __builtin_amdgcn_rcpf(1.f + e);
}
__device__ __forceinline__ float tanhf_(float x){
  float e = __expf(-2.f*fabsf(x));
  float r = (1.f - e)*__builtin_amdgcn_rcpf(1.f + e);
  return copysignf(r, x);
}

// ---------------- G row-normalize ----------------
__global__ void k_gnorm(const float* g0, const float* g1, const float* g2, const float* g3, float* gn){
  int t = threadIdx.x;
  if (t >= 96) return;
  int mat = t / 24, row = t % 24;
  const float* G = (mat==0)? g0 : (mat==1)? g1 : (mat==2)? g2 : g3;
  float s = 0.f;
  for (int m=0;m<24;m++) s += fabsf(G[row*24+m]);
  float inv = 1.f/s;
  for (int m=0;m<24;m++) gn[mat*576 + row*24 + m] = G[row*24+m]*inv;
}

// ---------------- weight transpose/cast + bias fold ----------------
__global__ void k_prep(const float* Wih, const float* Winit, const float* Whh, const float* Wfc,
                       const float* bih, const float* bhh,
                       ushort* wtp, ushort* wthh, ushort* wtfc, float* bgi){
  int stride = gridDim.x*blockDim.x;
  int t0 = blockIdx.x*blockDim.x + threadIdx.x;
  // W_ih (24,192,192) -> wtp[m][o][i]
  for (int f = t0; f < 884736; f += stride){
    int m = f/36864, rr = f - m*36864, o = rr/192, i = rr - o*192;
    wtp[((size_t)m*256 + o)*192 + i] = f2bf(Wih[(size_t)m*36864 + i*192 + o]);
  }
  // W_init (24,192,64) -> wtp[m][192+o][i]
  for (int f = t0; f < 294912; f += stride){
    int m = f/12288, rr = f - m*12288, o = rr/192, i = rr - o*192;
    wtp[((size_t)m*256 + 192 + o)*192 + i] = f2bf(Winit[(size_t)m*12288 + i*64 + o]);
  }
  // W_hh (24,64,192) -> wthh[m][o][i]
  for (int f = t0; f < 294912; f += stride){
    int m = f/12288, rr = f - m*12288, o = rr/64, i = rr - o*64;
    wthh[((size_t)m*192 + o)*64 + i] = f2bf(Whh[(size_t)m*12288 + i*192 + o]);
  }
  // W_fc (24,64,64) -> wtfc[m][o][i]
  for (int f = t0; f < 98304; f += stride){
    int m = f/4096, rr = f - m*4096, o = rr/64, i = rr - o*64;
    wtfc[((size_t)m*64 + o)*64 + i] = f2bf(Wfc[(size_t)m*4096 + i*64 + o]);
  }
  // folded gi bias: b_ih + b_hh on r,u slices only (n-gate's b_hh stays inside r*h_n)
  for (int f = t0; f < 4608; f += stride){
    int o = f % 192;
    bgi[f] = bih[f] + ((o<128) ? bhh[f] : 0.f);
  }
}

// ---------------- prolog per-node GEMM: rec(64b x 192) @ W^T -> t_ws ----------------
__global__ __launch_bounds__(256) void k_p1(const float* x, const float* h, const ushort* wtp,
                                            ushort* t_ws, int tsel, int o_base, int ntt){
  __shared__ ushort A_lds[64*192];
  int tid = threadIdx.x, w = tid>>6, l = tid&63;
  int m = blockIdx.x, b0 = blockIdx.y*64;
  for (int f = tid; f < 64*192; f += 256){
    int b = f/192, i = f - b*192;
    float v = (i < 64) ? x[((size_t)(b0+b)*3 + tsel)*1536 + m*64 + i]
                       : h[((size_t)(b0+b)*24 + m)*128 + (i-64)];
    A_lds[b*192 + (i ^ ((b&7)<<3))] = f2bf(v);
  }
  __syncthreads();
  for (int mt=0; mt<4; mt++){
    for (int nt = w; nt < ntt; nt += 4){
      f32x4 acc = {0.f,0.f,0.f,0.f};
      int rowb = mt*16 + (l&15);
      int og = o_base + nt*16 + (l&15);
      #pragma unroll
      for (int kc=0;kc<6;kc++){
        int i0 = kc*32 + ((l>>4)<<3);
        bf16x8 av = __builtin_bit_cast(bf16x8, *(const uint4*)(A_lds + rowb*192 + (i0 ^ ((rowb&7)<<3))));
        bf16x8 bv = __builtin_bit_cast(bf16x8, *(const uint4*)(wtp + ((size_t)m*256 + og)*192 + i0));
        acc = mfma16(av, bv, acc);
      }
      #pragma unroll
      for (int r=0;r<4;r++){
        int bp = mt*16 + ((l>>4)<<2) + r;
        t_ws[((size_t)(b0+bp)*24 + m)*256 + og] = f2bf(acc[r]);
      }
    }
  }
}

// ---------------- prolog mix: gi = Gn_ih @ t + bias ; h0 = Gn_init @ t + b_init ----------------
__global__ __launch_bounds__(256) void k_p2(const ushort* t_ws, const float* gn, const float* bgi,
                                            const float* binit, ushort* gi_ws, ushort* h0_ws){
  __shared__ ushort t_l[24*256];
  int tid = threadIdx.x; size_t b = blockIdx.x;
  const uint4* src = (const uint4*)(t_ws + b*6144);
  uint4* dst = (uint4*)t_l;
  for (int f = tid; f < 768; f += 256) dst[f] = src[f];
  __syncthreads();
  int o = tid;
  float acc[24];
  if (o < 192){
    const float* gih = gn + 576;
    #pragma unroll
    for (int n=0;n<24;n++) acc[n] = bgi[n*192+o];
    for (int m=0;m<24;m++){
      float tv = bf2f(t_l[m*256+o]);
      #pragma unroll
      for (int n=0;n<24;n++) acc[n] = fmaf(gih[n*24+m], tv, acc[n]);
    }
    uint ov[12];
    #pragma unroll
    for (int q=0;q<12;q++) ov[q] = (uint)f2bf(acc[2*q]) | ((uint)f2bf(acc[2*q+1])<<16);
    uint4* gdst = (uint4*)(gi_ws + (b*192 + o)*24);
    gdst[0] = make_uint4(ov[0],ov[1],ov[2],ov[3]);
    gdst[1] = make_uint4(ov[4],ov[5],ov[6],ov[7]);
    gdst[2] = make_uint4(ov[8],ov[9],ov[10],ov[11]);
  } else {
    int o2 = o - 192;
    const float* gin = gn;  // init
    #pragma unroll
    for (int n=0;n<24;n++) acc[n] = binit[n*64+o2];
    for (int m=0;m<24;m++){
      float tv = bf2f(t_l[m*256 + 192 + o2]);
      #pragma unroll
      for (int n=0;n<24;n++) acc[n] = fmaf(gin[n*24+m], tv, acc[n]);
    }
    #pragma unroll
    for (int n=0;n<24;n++) h0_ws[(b*24+n)*64 + o2] = f2bf(acc[n]);
  }
}

// ---------------- x_t passthrough ----------------
__global__ void k_copy(const float4* x, float4* out2){
  int i = blockIdx.x*blockDim.x + threadIdx.x;
  for (; i < 2048*384; i += gridDim.x*blockDim.x){
    int b = i/384; int r = i - b*384;
    out2[i] = x[(size_t)b*1152 + 768 + r];
  }
}

// ---------------- main persistent GRU loop: 128 blocks x 16-batch tile ----------------
__global__ __launch_bounds__(1024) void k_main(const ushort* gi_ws, const ushort* h0_ws,
    const ushort* wthh, const ushort* wtfc, const float* gn,
    const float* bhh, const float* bfc, float* out){
  __shared__ ushort h_l[24*16*64];     // [m][b][i], i XOR-swizzled by b  (49.2 KB)
  __shared__ ushort t_l[16*64*40];     // [c=(b,o)][m-slot 40], slots 24..39 = 0 (81.9 KB)
  __shared__ float bhn_l[1536];        // b_hh n-slice [n][j]
  __shared__ float bfc_l[1536];        // b_fc [n][o2]
  int tid = threadIdx.x, w = tid>>6, l = tid&63;
  int b0 = blockIdx.x*16;

  for (int f = tid; f < 1536; f += 1024){
    int n = f>>6, j = f&63;
    bhn_l[f] = bhh[n*192 + 128 + j];
    bfc_l[f] = bfc[f];
  }
  for (int f = tid; f < 16*64*16; f += 1024){   // zero K-pad slots (mix group 3 reads these)
    int c = f>>4, ms = 24 + (f&15);
    t_l[c*40 + ms] = 0;
  }
  for (int f4 = tid; f4 < 6144; f4 += 1024){    // stage h0 -> h_l (swizzled)
    int f = f4*4;
    int b = f/1536, r = f - b*1536, m = r>>6, i = r&63;
    ushort4 v = *(const ushort4*)(h0_ws + (size_t)(b0+b)*1536 + r);
    *(ushort4*)(h_l + ((m*16+b)<<6) + (i ^ ((b&7)<<3))) = v;
  }
  // constant Gn A-fragments (rows n, k=m; zero-padded to 32x16)
  bf16x8 gnhh[2], gnfc[2];
  #pragma unroll
  for (int nt2=0; nt2<2; nt2++){
    union { ushort s[8]; bf16x8 v; } uh, uf;
    int row = nt2*16 + (l&15);
    #pragma unroll
    for (int jj=0;jj<8;jj++){
      int k = ((l>>4)<<3) + jj;
      bool ok = (row<24) && (k<24);
      uh.s[jj] = ok ? f2bf(gn[2*576 + row*24 + k]) : (ushort)0;
      uf.s[jj] = ok ? f2bf(gn[3*576 + row*24 + k]) : (ushort)0;
    }
    gnhh[nt2] = uh.v; gnfc[nt2] = uf.v;
  }
  // per-lane gi registers in mix-C fragment layout
  ushort4 gi_pk[3][8];
  int cb[8], cj[8], cn0[8];
  #pragma unroll
  for (int ji=0;ji<8;ji++){
    int jd = w + ji*16;
    int c = (jd>>1)*16 + (l&15);
    cb[ji] = c>>6; cj[ji] = c&63; cn0[ji] = (jd&1)*16 + ((l>>4)<<2);
    #pragma unroll
    for (int g=0; g<3; g++)
      gi_pk[g][ji] = *(const ushort4*)(gi_ws + ((size_t)(b0+cb[ji])*192 + g*64 + cj[ji])*24 + cn0[ji]);
  }
  __syncthreads();
  // h_prev in registers (fragment layout)
  float hpv[8][4];
  #pragma unroll
  for (int ji=0;ji<8;ji++){
    #pragma unroll
    for (int r=0;r<4;r++){
      int n = cn0[ji] + r;
      hpv[ji][r] = (n<24) ? bf2f(h_l[((n*16+cb[ji])<<6) + (cj[ji] ^ ((cb[ji]&7)<<3))]) : 0.f;
    }
  }

  for (int step=0; step<16; step++){
    f32x4 racc[3][8];
    #pragma unroll
    for (int g=0; g<3; g++){
      __syncthreads();
      // per-node t-GEMM for this gate's 64 output cols
      #pragma unroll
      for (int ji=0; ji<6; ji++){
        int jd = w + ji*16;
        int m = jd>>2, nt = jd&3;
        f32x4 acc = {0.f,0.f,0.f,0.f};
        int rowb = l&15;
        int o = g*64 + nt*16 + (l&15);
        #pragma unroll
        for (int kh=0; kh<2; kh++){
          int i0 = kh*32 + ((l>>4)<<3);
          bf16x8 av = __builtin_bit_cast(bf16x8, *(const uint4*)(h_l + ((m*16+rowb)<<6) + (i0 ^ ((rowb&7)<<3))));
          bf16x8 bv = __builtin_bit_cast(bf16x8, *(const uint4*)(wthh + ((size_t)m*192 + o)*64 + i0));
          acc = mfma16(av, bv, acc);
        }
        int op = nt*16 + (l&15);
        #pragma unroll
        for (int r=0;r<4;r++){
          int bp = ((l>>4)<<2) + r;
          t_l[(bp*64 + op)*40 + m] = f2bf(acc[r]);
        }
      }
      __syncthreads();
      // node mix: Gn_hh(24x24pad) @ t -> gate pre-activation fragments
      #pragma unroll
      for (int ji=0; ji<8; ji++){
        int jd = w + ji*16;
        int nt2 = jd&1;
        int c = (jd>>1)*16 + (l&15);
        f32x4 cin;
        if (g<2){
          ushort4 gp = gi_pk[g][ji];
          cin[0]=bf2f(gp.x); cin[1]=bf2f(gp.y); cin[2]=bf2f(gp.z); cin[3]=bf2f(gp.w);
        } else {
          cin = (f32x4){0.f,0.f,0.f,0.f};
        }
        bf16x8 bv = __builtin_bit_cast(bf16x8, *(const uint4*)(t_l + c*40 + ((l>>4)<<3)));
        racc[g][ji] = mfma16(gnhh[nt2], bv, cin);
      }
    }
    // gate math fully in fragment registers
    #pragma unroll
    for (int ji=0; ji<8; ji++){
      int b = cb[ji], j = cj[ji], n0 = cn0[ji];
      ushort4 gp = gi_pk[2][ji];
      float gin[4] = { bf2f(gp.x), bf2f(gp.y), bf2f(gp.z), bf2f(gp.w) };
      #pragma unroll
      for (int r=0;r<4;r++){
        int n = n0 + r;
        float rg = sigmoidf_(racc[0][ji][r]);
        float ug = sigmoidf_(racc[1][ji][r]);
        float hn = racc[2][ji][r] + ((n<24) ? bhn_l[(n<<6)+j] : 0.f);
        float nn = tanhf_(gin[r] + rg*hn);
        float hv = (1.f-ug)*nn + ug*hpv[ji][r];
        hpv[ji][r] = hv;
        if (n < 24) h_l[((n*16+b)<<6) + (j ^ ((b&7)<<3))] = f2bf(hv);
      }
    }
    __syncthreads();
    // fc t2-GEMM
    #pragma unroll
    for (int ji=0; ji<6; ji++){
      int jd = w + ji*16;
      int m = jd>>2, nt = jd&3;
      f32x4 acc = {0.f,0.f,0.f,0.f};
      int rowb = l&15;
      int o2 = nt*16 + (l&15);
      #pragma unroll
      for (int kh=0; kh<2; kh++){
        int i0 = kh*32 + ((l>>4)<<3);
        bf16x8 av = __builtin_bit_cast(bf16x8, *(const uint4*)(h_l + ((m*16+rowb)<<6) + (i0 ^ ((rowb&7)<<3))));
        bf16x8 bv = __builtin_bit_cast(bf16x8, *(const uint4*)(wtfc + ((size_t)m*64 + o2)*64 + i0));
        acc = mfma16(av, bv, acc);
      }
      #pragma unroll
      for (int r=0;r<4;r++){
        int bp = ((l>>4)<<2) + r;
        t_l[(bp*64 + o2)*40 + m] = f2bf(acc[r]);
      }
    }
    __syncthreads();
    // fc mix + tanh + store
    #pragma unroll
    for (int ji=0; ji<8; ji++){
      int jd = w + ji*16;
      int nt2 = jd&1;
      int c = (jd>>1)*16 + (l&15);
      int b = cb[ji], o2 = cj[ji], n0 = cn0[ji];
      f32x4 z = {0.f,0.f,0.f,0.f};
      bf16x8 bv = __builtin_bit_cast(bf16x8, *(const uint4*)(t_l + c*40 + ((l>>4)<<3)));
      f32x4 fa = mfma16(gnfc[nt2], bv, z);
      #pragma unroll
      for (int r=0;r<4;r++){
        int n = n0 + r;
        if (n < 24){
          float y = tanhf_(fa[r] + bfc_l[(n<<6)+o2]);
          out[(((size_t)(b0+b)*16 + step)*1536) + (n<<6) + o2] = y;
        }
      }
    }
  }
}

extern "C" void kernel_launch(void* const* d_in, const int* in_sizes, int n_in,
                              void* d_out, int out_size, void* d_ws, size_t ws_size,
                              hipStream_t stream){
  if (ws_size < WS_NEED) return;  // fail loudly (output stays poisoned)
  const float* x     = (const float*)d_in[0];
  const float* h     = (const float*)d_in[1];
  const float* Winit = (const float*)d_in[4];
  const float* binit = (const float*)d_in[5];
  const float* Ginit = (const float*)d_in[6];
  const float* Wih   = (const float*)d_in[7];
  const float* bih   = (const float*)d_in[8];
  const float* Gih   = (const float*)d_in[9];
  const float* Whh   = (const float*)d_in[10];
  const float* bhh   = (const float*)d_in[11];
  const float* Ghh   = (const float*)d_in[12];
  const float* Wfc   = (const float*)d_in[13];
  const float* bfc   = (const float*)d_in[14];
  const float* Gfc   = (const float*)d_in[15];
  char* ws = (char*)d_ws;
  ushort* wtp  = (ushort*)(ws + WTP_OFF);
  ushort* wthh = (ushort*)(ws + WTHH_OFF);
  ushort* wtfc = (ushort*)(ws + WTFC_OFF);
  float*  gn   = (float*)(ws + GN_OFF);
  float*  bgi  = (float*)(ws + BGI_OFF);
  ushort* tws  = (ushort*)(ws + TWS_OFF);
  ushort* giws = (ushort*)(ws + GIWS_OFF);
  ushort* h0ws = (ushort*)(ws + H0WS_OFF);
  float* out  = (float*)d_out;
  float* out2 = out + (size_t)2048*16*1536;

  k_gnorm<<<1, 128, 0, stream>>>(Ginit, Gih, Ghh, Gfc, gn);
  k_prep<<<512, 256, 0, stream>>>(Wih, Winit, Whh, Wfc, bih, bhh, wtp, wthh, wtfc, bgi);
  k_p1<<<dim3(24,32), 256, 0, stream>>>(x, h, wtp, tws, 2, 0, 12);    // gi pre-mix (uses x_t)
  k_p1<<<dim3(24,32), 256, 0, stream>>>(x, h, wtp, tws, 1, 192, 4);   // h0 pre-mix (uses x_{t-1})
  k_p2<<<2048, 256, 0, stream>>>(tws, gn, bgi, binit, giws, h0ws);
  k_copy<<<2048, 256, 0, stream>>>((const float4*)x, (float4*)out2);
  k_main<<<128, 1024, 0, stream>>>(giws, h0ws, wthh, wtfc, gn, bhh, bfc, out);
}

// Round 2
// 823.711 us; speedup vs baseline: 1.7206x; 1.7206x over previous
//
#include <hip/hip_runtime.h>
#include <hip/hip_bf16.h>
#include <cstdint>

typedef __bf16 bf16x8 __attribute__((ext_vector_type(8)));
typedef float  f32x4  __attribute__((ext_vector_type(4)));

// ---------------- workspace layout (bytes) ----------------
constexpr size_t WTP_OFF  = 0;         // [24][256][192] bf16 prolog W^T
constexpr size_t WTHH_OFF = 2359296;   // [24][192][64]  bf16 W_hh^T per node
constexpr size_t WTFC_OFF = 2949120;   // [24][64][64]   bf16 W_fc^T per node
constexpr size_t GN_OFF   = 3145728;   // [4][24][24] f32 row-L1-normalized
constexpr size_t BGI_OFF  = 3154944;   // [24][192] f32 folded gi bias
constexpr size_t BHN2_OFF = 3173376;   // [64 j][24 n] f32 b_hh n-slice, n-contig
constexpr size_t BFC2_OFF = 3179520;   // [64 o][24 n] f32 b_fc, n-contig
constexpr size_t TWS_OFF  = 3185664;   // [2048][24][256] bf16 prolog GEMM result
constexpr size_t GIWS_OFF = 28351488;  // [2048][192][24] bf16 gi (n innermost)
constexpr size_t H0WS_OFF = 47225856;  // [2048][24][64] bf16 h0
constexpr size_t WS_NEED  = 53517312;

// 16B-block XOR swizzle for t_l: c in [0,512), q = m>>3 in [0,4); blk in [0,8)
#define BLK(c,q) ((((q) ^ ((c)&3)) | ((((c)>>2)&1)<<2)))
// h_l address (ushort index): [n][b][i] with i XOR-swizzled by b and n
#define HL(n,b,i) ((((n)*8+(b))<<6) + ((i) ^ (((b)&7)<<3) ^ ((((n)>>2)&3)<<4)))

__device__ __forceinline__ float bf2f(ushort u){
  union { uint32_t i; float f; } v; v.i = ((uint32_t)u) << 16; return v.f;
}
__device__ __forceinline__ ushort f2bf(float f){
  union { float f; uint32_t i; } v; v.f = f;
  return (ushort)((v.i + 0x7fffu + ((v.i >> 16) & 1u)) >> 16);
}
__device__ __forceinline__ f32x4 mfma16(bf16x8 a, bf16x8 b, f32x4 c){
  return __builtin_amdgcn_mfma_f32_16x16x32_bf16(a, b, c, 0, 0, 0);
}
__device__ __forceinline__ float sigmoidf_(float x){
  float e = __expf(-x); return __builtin_amdgcn_rcpf(1.f + e);
}
__device__ __forceinline__ float tanhf_(float x){
  float e = __expf(-2.f*fabsf(x));
  float r = (1.f - e)*__builtin_amdgcn_rcpf(1.f + e);
  return copysignf(r, x);
}

// ---------------- G row-normalize ----------------
__global__ void k_gnorm(const float* g0, const float* g1, const float* g2, const float* g3, float* gn){
  int t = threadIdx.x;
  if (t >= 96) return;
  int mat = t / 24, row = t % 24;
  const float* G = (mat==0)? g0 : (mat==1)? g1 : (mat==2)? g2 : g3;
  float s = 0.f;
  for (int m=0;m<24;m++) s += fabsf(G[row*24+m]);
  float inv = 1.f/s;
  for (int m=0;m<24;m++) gn[mat*576 + row*24 + m] = G[row*24+m]*inv;
}

// ---------------- weight transpose/cast + bias prep ----------------
__global__ void k_prep(const float* Wih, const float* Winit, const float* Whh, const float* Wfc,
                       const float* bih, const float* bhh, const float* bfc,
                       ushort* wtp, ushort* wthh, ushort* wtfc, float* bgi,
                       float* bhn2, float* bfc2){
  int stride = gridDim.x*blockDim.x;
  int t0 = blockIdx.x*blockDim.x + threadIdx.x;
  for (int f = t0; f < 884736; f += stride){
    int m = f/36864, rr = f - m*36864, o = rr/192, i = rr - o*192;
    wtp[((size_t)m*256 + o)*192 + i] = f2bf(Wih[(size_t)m*36864 + i*192 + o]);
  }
  for (int f = t0; f < 294912; f += stride){
    int m = f/12288, rr = f - m*12288, o = rr/192, i = rr - o*192;
    wtp[((size_t)m*256 + 192 + o)*192 + i] = f2bf(Winit[(size_t)m*12288 + i*64 + o]);
  }
  for (int f = t0; f < 294912; f += stride){
    int m = f/12288, rr = f - m*12288, o = rr/64, i = rr - o*64;
    wthh[((size_t)m*192 + o)*64 + i] = f2bf(Whh[(size_t)m*12288 + i*192 + o]);
  }
  for (int f = t0; f < 98304; f += stride){
    int m = f/4096, rr = f - m*4096, o = rr/64, i = rr - o*64;
    wtfc[((size_t)m*64 + o)*64 + i] = f2bf(Wfc[(size_t)m*4096 + i*64 + o]);
  }
  for (int f = t0; f < 4608; f += stride){
    int o = f % 192;
    bgi[f] = bih[f] + ((o<128) ? bhh[f] : 0.f);
  }
  for (int f = t0; f < 1536; f += stride){
    int o = f/24, n = f - o*24;
    bhn2[f] = bhh[n*192 + 128 + o];
    bfc2[f] = bfc[n*64 + o];
  }
}

// ---------------- prolog per-node GEMM: rec(64b x 192) @ W^T -> t_ws ----------------
__global__ __launch_bounds__(256) void k_p1(const float* x, const float* h, const ushort* wtp,
                                            ushort* t_ws, int tsel, int o_base, int ntt){
  __shared__ ushort A_lds[64*192];
  int tid = threadIdx.x, w = tid>>6, l = tid&63;
  int m = blockIdx.x, b0 = blockIdx.y*64;
  for (int f = tid; f < 64*192; f += 256){
    int b = f/192, i = f - b*192;
    float v = (i < 64) ? x[((size_t)(b0+b)*3 + tsel)*1536 + m*64 + i]
                       : h[((size_t)(b0+b)*24 + m)*128 + (i-64)];
    A_lds[b*192 + (i ^ ((b&7)<<3))] = f2bf(v);
  }
  __syncthreads();
  for (int mt=0; mt<4; mt++){
    for (int nt = w; nt < ntt; nt += 4){
      f32x4 acc = {0.f,0.f,0.f,0.f};
      int rowb = mt*16 + (l&15);
      int og = o_base + nt*16 + (l&15);
      #pragma unroll
      for (int kc=0;kc<6;kc++){
        int i0 = kc*32 + ((l>>4)<<3);
        bf16x8 av = __builtin_bit_cast(bf16x8, *(const uint4*)(A_lds + rowb*192 + (i0 ^ ((rowb&7)<<3))));
        bf16x8 bv = __builtin_bit_cast(bf16x8, *(const uint4*)(wtp + ((size_t)m*256 + og)*192 + i0));
        acc = mfma16(av, bv, acc);
      }
      #pragma unroll
      for (int r=0;r<4;r++){
        int bp = mt*16 + ((l>>4)<<2) + r;
        t_ws[((size_t)(b0+bp)*24 + m)*256 + og] = f2bf(acc[r]);
      }
    }
  }
}

// ---------------- prolog mix: gi = Gn_ih @ t + bias ; h0 = Gn_init @ t + b_init ----------------
__global__ __launch_bounds__(256) void k_p2(const ushort* t_ws, const float* gn, const float* bgi,
                                            const float* binit, ushort* gi_ws, ushort* h0_ws){
  __shared__ ushort t_l[24*256];
  int tid = threadIdx.x; size_t b = blockIdx.x;
  const uint4* src = (const uint4*)(t_ws + b*6144);
  uint4* dst = (uint4*)t_l;
  for (int f = tid; f < 768; f += 256) dst[f] = src[f];
  __syncthreads();
  int o = tid;
  float acc[24];
  if (o < 192){
    const float* gih = gn + 576;
    #pragma unroll
    for (int n=0;n<24;n++) acc[n] = bgi[n*192+o];
    for (int m=0;m<24;m++){
      float tv = bf2f(t_l[m*256+o]);
      #pragma unroll
      for (int n=0;n<24;n++) acc[n] = fmaf(gih[n*24+m], tv, acc[n]);
    }
    uint ov[12];
    #pragma unroll
    for (int q=0;q<12;q++) ov[q] = (uint)f2bf(acc[2*q]) | ((uint)f2bf(acc[2*q+1])<<16);
    uint4* gdst = (uint4*)(gi_ws + (b*192 + o)*24);
    gdst[0] = make_uint4(ov[0],ov[1],ov[2],ov[3]);
    gdst[1] = make_uint4(ov[4],ov[5],ov[6],ov[7]);
    gdst[2] = make_uint4(ov[8],ov[9],ov[10],ov[11]);
  } else {
    int o2 = o - 192;
    const float* gin = gn;
    #pragma unroll
    for (int n=0;n<24;n++) acc[n] = binit[n*64+o2];
    for (int m=0;m<24;m++){
      float tv = bf2f(t_l[m*256 + 192 + o2]);
      #pragma unroll
      for (int n=0;n<24;n++) acc[n] = fmaf(gin[n*24+m], tv, acc[n]);
    }
    #pragma unroll
    for (int n=0;n<24;n++) h0_ws[(b*24+n)*64 + o2] = f2bf(acc[n]);
  }
}

// ---------------- x_t passthrough ----------------
__global__ void k_copy(const float4* x, float4* out2){
  int i = blockIdx.x*blockDim.x + threadIdx.x;
  for (; i < 2048*384; i += gridDim.x*blockDim.x){
    int b = i/384; int r = i - b*384;
    out2[i] = x[(size_t)b*1152 + 768 + r];
  }
}

// ---------------- main GRU loop: 256 blocks x 8-batch tile, 8 waves ----------------
__global__ __launch_bounds__(512,2) void k_main(const ushort* giws, const ushort* h0ws,
    const ushort* wthh, const ushort* wtfc, const float* gn,
    const float* bhn2, const float* bfc2, float* out){
  __shared__ ushort h_l[12288];   // 24n x 8b x 64i, swizzled (24.6 KB)
  __shared__ ushort t_l[32768];   // 512c x 64: XOR 16B-block layout (64 KB)
  const int tid = threadIdx.x, w = tid>>6, l = tid&63;
  const int lr = l&15, lq = l>>4;
  const int b0 = blockIdx.x*8;

  // zero the q=3 (m=24..31) pad octets once
  for (int f = tid; f < 4096; f += 512){
    int c = f>>3, mm = f&7;
    t_l[(c<<6) + (BLK(c,3)<<3) + mm] = 0;
  }
  // stage h0 -> h_l (swizzled)
  for (int f = tid; f < 3072; f += 512){
    int idx = f<<2; int b = idx/1536; int r2 = idx - b*1536; int n = r2>>6; int i = r2&63;
    ushort4 v = *(const ushort4*)(h0ws + (size_t)(b0+b)*1536 + r2);
    *(ushort4*)(h_l + HL(n,b,i)) = v;
  }
  // constant Gn A-fragments (rows n, k=m, zero-padded)
  bf16x8 gnhh[2], gnfc[2];
  #pragma unroll
  for (int nt2=0; nt2<2; nt2++){
    union { ushort s[8]; bf16x8 v; } uh, uf;
    int row = nt2*16 + lr;
    #pragma unroll
    for (int jj=0;jj<8;jj++){
      int m = lq*8 + jj;
      bool ok = (row<24) && (m<24);
      uh.s[jj] = ok ? f2bf(gn[2*576 + row*24 + m]) : (ushort)0;
      uf.s[jj] = ok ? f2bf(gn[3*576 + row*24 + m]) : (ushort)0;
    }
    gnhh[nt2] = uh.v; gnfc[nt2] = uf.v;
  }
  // hoist gi fragments (step-invariant): [gate][task]
  ushort4 gih[3][8];
  #pragma unroll
  for (int k=0;k<8;k++){
    int tId = w + k*8, ct = tId>>1, nt2 = tId&1;
    int c = ct*16 + lr, b = c>>6, o = c&63, n0 = nt2*16 + lq*4;
    size_t base = ((size_t)(b0+b)*192 + o)*24 + n0;
    gih[0][k] = *(const ushort4*)(giws + base);
    gih[1][k] = *(const ushort4*)(giws + base + 64*24);
    gih[2][k] = *(const ushort4*)(giws + base + 128*24);
  }
  __syncthreads();

  float Rg[8][4], Ug[8][4];
  for (int step=0; step<16; step++){
    #pragma unroll 1
    for (int g=0; g<3; g++){
      __syncthreads();
      // per-node t-GEMM (12 tasks/wave), weights streamed from L2
      #pragma unroll
      for (int k=0;k<12;k++){
        int tId = w + k*8, m = tId>>2, nt = tId&3;
        int o_loc = nt*16 + lr;
        const ushort* wb = wthh + (((size_t)m*192 + g*64 + o_loc)<<6);
        f32x4 acc = {0.f,0.f,0.f,0.f};
        #pragma unroll
        for (int kh=0;kh<2;kh++){
          int i0 = kh*32 + lq*8;
          bf16x8 av = __builtin_bit_cast(bf16x8, *(const uint4*)(h_l + HL(m, lr&7, i0)));
          bf16x8 bv = __builtin_bit_cast(bf16x8, *(const uint4*)(wb + i0));
          acc = mfma16(av, bv, acc);
        }
        if (l < 32){
          #pragma unroll
          for (int r=0;r<4;r++){
            int bp = lq*4 + r, c = (bp<<6) + o_loc;
            t_l[(c<<6) + (BLK(c, m>>3)<<3) + (m&7)] = f2bf(acc[r]);
          }
        }
      }
      __syncthreads();
      // node mix (8 tasks/wave) + gate math on g==2
      #pragma unroll
      for (int k=0;k<8;k++){
        int tId = w + k*8, ct = tId>>1, nt2 = tId&1;
        int c = ct*16 + lr, b = c>>6, o = c&63, n0 = nt2*16 + lq*4;
        f32x4 cin;
        if (g < 2){
          ushort4 gp = gih[g][k];
          cin[0]=bf2f(gp.x); cin[1]=bf2f(gp.y); cin[2]=bf2f(gp.z); cin[3]=bf2f(gp.w);
        } else {
          cin = *(const f32x4*)(bhn2 + o*24 + n0);
        }
        bf16x8 bv = __builtin_bit_cast(bf16x8, *(const uint4*)(t_l + (c<<6) + (BLK(c,lq)<<3)));
        f32x4 fa = mfma16(gnhh[nt2], bv, cin);
        if (g == 0){
          #pragma unroll
          for (int r=0;r<4;r++) Rg[k][r] = sigmoidf_(fa[r]);
        } else if (g == 1){
          #pragma unroll
          for (int r=0;r<4;r++) Ug[k][r] = sigmoidf_(fa[r]);
        } else {
          ushort4 gp = gih[2][k];
          float gin[4] = { bf2f(gp.x), bf2f(gp.y), bf2f(gp.z), bf2f(gp.w) };
          #pragma unroll
          for (int r=0;r<4;r++){
            int n = n0 + r;
            if (n < 24){
              float nn = tanhf_(gin[r] + Rg[k][r]*fa[r]);
              float hp = bf2f(h_l[HL(n,b,o)]);
              float hv = (1.f-Ug[k][r])*nn + Ug[k][r]*hp;
              h_l[HL(n,b,o)] = f2bf(hv);
            }
          }
        }
      }
    }
    __syncthreads();
    // fc t2-GEMM
    #pragma unroll
    for (int k=0;k<12;k++){
      int tId = w + k*8, m = tId>>2, nt = tId&3;
      int o_loc = nt*16 + lr;
      const ushort* wb = wtfc + ((((size_t)m<<6) + o_loc)<<6);
      f32x4 acc = {0.f,0.f,0.f,0.f};
      #pragma unroll
      for (int kh=0;kh<2;kh++){
        int i0 = kh*32 + lq*8;
        bf16x8 av = __builtin_bit_cast(bf16x8, *(const uint4*)(h_l + HL(m, lr&7, i0)));
        bf16x8 bv = __builtin_bit_cast(bf16x8, *(const uint4*)(wb + i0));
        acc = mfma16(av, bv, acc);
      }
      if (l < 32){
        #pragma unroll
        for (int r=0;r<4;r++){
          int bp = lq*4 + r, c = (bp<<6) + o_loc;
          t_l[(c<<6) + (BLK(c, m>>3)<<3) + (m&7)] = f2bf(acc[r]);
        }
      }
    }
    __syncthreads();
    // fc mix + tanh + store
    #pragma unroll
    for (int k=0;k<8;k++){
      int tId = w + k*8, ct = tId>>1, nt2 = tId&1;
      int c = ct*16 + lr, b = c>>6, o = c&63, n0 = nt2*16 + lq*4;
      f32x4 cin = *(const f32x4*)(bfc2 + o*24 + n0);
      bf16x8 bv = __builtin_bit_cast(bf16x8, *(const uint4*)(t_l + (c<<6) + (BLK(c,lq)<<3)));
      f32x4 fa = mfma16(gnfc[nt2], bv, cin);
      #pragma unroll
      for (int r=0;r<4;r++){
        int n = n0 + r;
        if (n < 24){
          out[((size_t)(b0+b)*16 + step)*1536 + (n<<6) + o] = tanhf_(fa[r]);
        }
      }
    }
  }
}

extern "C" void kernel_launch(void* const* d_in, const int* in_sizes, int n_in,
                              void* d_out, int out_size, void* d_ws, size_t ws_size,
                              hipStream_t stream){
  if (ws_size < WS_NEED) return;
  const float* x     = (const float*)d_in[0];
  const float* h     = (const float*)d_in[1];
  const float* Winit = (const float*)d_in[4];
  const float* binit = (const float*)d_in[5];
  const float* Ginit = (const float*)d_in[6];
  const float* Wih   = (const float*)d_in[7];
  const float* bih   = (const float*)d_in[8];
  const float* Gih   = (const float*)d_in[9];
  const float* Whh   = (const float*)d_in[10];
  const float* bhh   = (const float*)d_in[11];
  const float* Ghh   = (const float*)d_in[12];
  const float* Wfc   = (const float*)d_in[13];
  const float* bfc   = (const float*)d_in[14];
  const float* Gfc   = (const float*)d_in[15];
  char* ws = (char*)d_ws;
  ushort* wtp  = (ushort*)(ws + WTP_OFF);
  ushort* wthh = (ushort*)(ws + WTHH_OFF);
  ushort* wtfc = (ushort*)(ws + WTFC_OFF);
  float*  gn   = (float*)(ws + GN_OFF);
  float*  bgi  = (float*)(ws + BGI_OFF);
  float*  bhn2 = (float*)(ws + BHN2_OFF);
  float*  bfc2 = (float*)(ws + BFC2_OFF);
  ushort* tws  = (ushort*)(ws + TWS_OFF);
  ushort* giws = (ushort*)(ws + GIWS_OFF);
  ushort* h0ws = (ushort*)(ws + H0WS_OFF);
  float* out  = (float*)d_out;
  float* out2 = out + (size_t)2048*16*1536;

  k_gnorm<<<1, 128, 0, stream>>>(Ginit, Gih, Ghh, Gfc, gn);
  k_prep<<<512, 256, 0, stream>>>(Wih, Winit, Whh, Wfc, bih, bhh, bfc, wtp, wthh, wtfc, bgi, bhn2, bfc2);
  k_p1<<<dim3(24,32), 256, 0, stream>>>(x, h, wtp, tws, 2, 0, 12);
  k_p1<<<dim3(24,32), 256, 0, stream>>>(x, h, wtp, tws, 1, 192, 4);
  k_p2<<<2048, 256, 0, stream>>>(tws, gn, bgi, binit, giws, h0ws);
  k_copy<<<2048, 256, 0, stream>>>((const float4*)x, (float4*)out2);
  k_main<<<256, 512, 0, stream>>>(giws, h0ws, wthh, wtfc, gn, bhn2, bfc2, out);
}